// Round 1
// baseline (1331.746 us; speedup 1.0000x reference)
//
#include <hip/hip_runtime.h>
#include <hip/hip_bf16.h>
#include <math.h>

// Problem constants
#define Bsz 8
#define Lseq 2048
#define ENC_IN 21
#define C_OUT 21
#define D_MODEL 512
#define D_INNER 1024
#define D_STATE 16
#define D_CONV 4
#define DT_RANK 32
#define MARK_DIM 4
#define PRED_LEN 96
#define L_TAIL (Lseq - PRED_LEN)   // 1952

// ---------------------------------------------------------------------------
// 1) Instance-norm stats: mean/std over time per (b, c)
// ---------------------------------------------------------------------------
__global__ void stats_kernel(const float* __restrict__ x_enc,
                             float* __restrict__ mean, float* __restrict__ stdv) {
    int bc = blockIdx.x;               // 0..167
    int b = bc / ENC_IN, c = bc % ENC_IN;
    __shared__ float red[256];
    int t = threadIdx.x;
    float s = 0.f;
    for (int l = t; l < Lseq; l += 256)
        s += x_enc[((size_t)b * Lseq + l) * ENC_IN + c];
    red[t] = s; __syncthreads();
    for (int off = 128; off > 0; off >>= 1) {
        if (t < off) red[t] += red[t + off];
        __syncthreads();
    }
    float m = red[0] / (float)Lseq;
    __syncthreads();
    float v = 0.f;
    for (int l = t; l < Lseq; l += 256) {
        float d = x_enc[((size_t)b * Lseq + l) * ENC_IN + c] - m;
        v += d * d;
    }
    red[t] = v; __syncthreads();
    for (int off = 128; off > 0; off >>= 1) {
        if (t < off) red[t] += red[t + off];
        __syncthreads();
    }
    if (t == 0) {
        mean[bc] = m;
        stdv[bc] = sqrtf(red[0] / (float)Lseq + 1e-5f);
    }
}

// ---------------------------------------------------------------------------
// 2) Fuse head_w @ out_proj_w -> W (21 x 1024)
// ---------------------------------------------------------------------------
__global__ void fuse_w_kernel(const float* __restrict__ head_w,
                              const float* __restrict__ out_proj_w,
                              float* __restrict__ W) {
    int idx = blockIdx.x * 256 + threadIdx.x;
    if (idx >= C_OUT * D_INNER) return;
    int c = idx / D_INNER, d = idx % D_INNER;
    float s = 0.f;
    for (int k = 0; k < D_MODEL; ++k)
        s += head_w[c * D_MODEL + k] * out_proj_w[(size_t)k * D_INNER + d];
    W[idx] = s;
}

// ---------------------------------------------------------------------------
// 3) Embedding: circular conv(k=3) of normalized input + temporal emb + pos emb
//    one block per (b,l); 256 threads cover d = 0..511
// ---------------------------------------------------------------------------
__global__ void embed_kernel(const float* __restrict__ x_enc,
                             const float* __restrict__ x_mark,
                             const float* __restrict__ conv_w,
                             const float* __restrict__ temp_w,
                             const float* __restrict__ mean,
                             const float* __restrict__ stdv,
                             float* __restrict__ emb) {
    int bl = blockIdx.x;
    int b = bl >> 11, l = bl & (Lseq - 1);
    __shared__ float xs[3 * ENC_IN + MARK_DIM];
    int t = threadIdx.x;
    if (t < 3 * ENC_IN) {
        int k = t / ENC_IN, c = t % ENC_IN;
        int ll = (l + k - 1 + Lseq) & (Lseq - 1);     // circular
        xs[t] = (x_enc[((size_t)b * Lseq + ll) * ENC_IN + c] - mean[b * ENC_IN + c])
                / stdv[b * ENC_IN + c];
    } else if (t < 3 * ENC_IN + MARK_DIM) {
        xs[t] = x_mark[((size_t)b * Lseq + l) * MARK_DIM + (t - 3 * ENC_IN)];
    }
    __syncthreads();
    for (int d = t; d < D_MODEL; d += 256) {
        float v = 0.f;
        #pragma unroll
        for (int k = 0; k < 3; ++k)
            #pragma unroll
            for (int c = 0; c < ENC_IN; ++c)
                v += xs[k * ENC_IN + c] * conv_w[((size_t)d * ENC_IN + c) * 3 + k];
        #pragma unroll
        for (int m = 0; m < MARK_DIM; ++m)
            v += xs[3 * ENC_IN + m] * temp_w[d * MARK_DIM + m];
        // positional encoding
        int i = d >> 1;
        float div = expf((float)(2 * i) * (-9.210340371976184f / (float)D_MODEL));
        float ang = (float)l * div;
        v += (d & 1) ? cosf(ang) : sinf(ang);
        emb[(size_t)bl * D_MODEL + d] = v;
    }
}

// ---------------------------------------------------------------------------
// 4) Generic fp32 tiled GEMM, C[M,N] = A[M,K] @ B[N,K]^T  (both row-major)
//    BM=BN=64, BK=16, 256 threads, 4x4 per thread.
//    EPI 0: plain store to C0 (ld = N)
//    EPI 2: bias + softplus, store to C0
//    EPI 3: A-rows remapped to the last-96 slice (r -> b*2048 + 1952 + r%96)
// ---------------------------------------------------------------------------
template <int EPI>
__launch_bounds__(256)
__global__ void gemm_nt(const float* __restrict__ A, const float* __restrict__ B,
                        float* __restrict__ C0, const float* __restrict__ bias,
                        int M, int N, int K, int lda, int ldb) {
    __shared__ float As[16][65];
    __shared__ float Bs[16][65];
    int bm = blockIdx.y, bn = blockIdx.x;
    int t = threadIdx.x;
    int tx = t & 15, ty = t >> 4;
    float acc[4][4] = {};
    int arow = bm * 64, bcol = bn * 64;
    int lr = t >> 2;          // 0..63
    int lk = (t & 3) * 4;     // 0,4,8,12

    // resolve (possibly remapped) global A row for this loader thread
    size_t aRow;
    {
        int r = arow + lr;
        if (EPI == 3) {
            int rb = r / PRED_LEN;
            int rl = r - rb * PRED_LEN;
            aRow = (size_t)rb * Lseq + L_TAIL + rl;
        } else {
            aRow = (size_t)r;
        }
    }
    size_t bRow = (size_t)(bcol + lr);

    for (int k0 = 0; k0 < K; k0 += 16) {
        float4 av = *(const float4*)(A + aRow * lda + k0 + lk);
        float4 bv = *(const float4*)(B + bRow * ldb + k0 + lk);
        As[lk + 0][lr] = av.x; As[lk + 1][lr] = av.y;
        As[lk + 2][lr] = av.z; As[lk + 3][lr] = av.w;
        Bs[lk + 0][lr] = bv.x; Bs[lk + 1][lr] = bv.y;
        Bs[lk + 2][lr] = bv.z; Bs[lk + 3][lr] = bv.w;
        __syncthreads();
        #pragma unroll
        for (int kk = 0; kk < 16; ++kk) {
            float a[4], bq[4];
            #pragma unroll
            for (int i = 0; i < 4; ++i) a[i] = As[kk][ty * 4 + i];
            #pragma unroll
            for (int j = 0; j < 4; ++j) bq[j] = Bs[kk][tx * 4 + j];
            #pragma unroll
            for (int i = 0; i < 4; ++i)
                #pragma unroll
                for (int j = 0; j < 4; ++j)
                    acc[i][j] += a[i] * bq[j];
        }
        __syncthreads();
    }

    #pragma unroll
    for (int i = 0; i < 4; ++i) {
        int row = arow + ty * 4 + i;
        #pragma unroll
        for (int j = 0; j < 4; ++j) {
            int col = bcol + tx * 4 + j;
            float v = acc[i][j];
            if (EPI == 2) {
                v += bias[col];
                v = (v > 20.f) ? v : log1pf(expf(v));
            }
            C0[(size_t)row * N + col] = v;
        }
    }
}

// ---------------------------------------------------------------------------
// 5) Depthwise causal conv1d (k=4) + SiLU
// ---------------------------------------------------------------------------
__global__ void dwconv_kernel(const float* __restrict__ xs_raw,
                              const float* __restrict__ w,
                              const float* __restrict__ bias,
                              float* __restrict__ out) {
    size_t idx = (size_t)blockIdx.x * 256 + threadIdx.x;
    if (idx >= (size_t)Bsz * Lseq * D_INNER) return;
    int d = idx & (D_INNER - 1);
    size_t bl = idx >> 10;
    int l = (int)(bl & (Lseq - 1));
    float acc = bias[d];
    #pragma unroll
    for (int k = 0; k < D_CONV; ++k) {
        int ll = l - (D_CONV - 1) + k;
        if (ll >= 0)
            acc += xs_raw[(bl - (D_CONV - 1) + k) * D_INNER + d] * w[d * D_CONV + k];
    }
    out[idx] = acc / (1.f + __expf(-acc));   // SiLU
}

// ---------------------------------------------------------------------------
// 6) Selective scan. Lane = one (d, n) state. 16 lanes per d-channel.
//    Block: 256 threads = 16 d-channels. Grid: 8 b * 64 d-groups.
//    Emits y only for l >= L_TAIL, fused with +u*D and *silu(z).
// ---------------------------------------------------------------------------
__launch_bounds__(256)
__global__ void scan_kernel(const float* __restrict__ delta,
                            const float* __restrict__ u,
                            const float* __restrict__ xdbl,
                            const float* __restrict__ A_log,
                            const float* __restrict__ Dp,
                            const float* __restrict__ z96,
                            float* __restrict__ y96) {
    int b = blockIdx.x >> 6;
    int dg = blockIdx.x & 63;
    int t = threadIdx.x;
    int d = dg * 16 + (t >> 4);
    int n = t & 15;
    float A = -__expf(A_log[d * D_STATE + n]);
    float Dd = Dp[d];
    float h = 0.f;
    const size_t rowD = (size_t)b * Lseq * D_INNER + d;
    const size_t rowX = (size_t)b * Lseq * 64;

    for (int l0 = 0; l0 < Lseq; l0 += 4) {
        float dl[4], uu[4], Bv[4], Cv[4];
        #pragma unroll
        for (int j = 0; j < 4; ++j) {
            size_t off = rowD + (size_t)(l0 + j) * D_INNER;
            dl[j] = delta[off];
            uu[j] = u[off];
            Bv[j] = xdbl[rowX + (size_t)(l0 + j) * 64 + DT_RANK + n];
            Cv[j] = xdbl[rowX + (size_t)(l0 + j) * 64 + DT_RANK + D_STATE + n];
        }
        #pragma unroll
        for (int j = 0; j < 4; ++j) {
            int l = l0 + j;
            h = __expf(dl[j] * A) * h + (dl[j] * uu[j]) * Bv[j];
            if (l >= L_TAIL) {
                float y = h * Cv[j];
                #pragma unroll
                for (int m = 8; m >= 1; m >>= 1) y += __shfl_xor(y, m, 16);
                if (n == 0) {
                    size_t o = ((size_t)b * PRED_LEN + (l - L_TAIL)) * D_INNER + d;
                    float z = z96[o];
                    y96[o] = (y + uu[j] * Dd) * (z / (1.f + __expf(-z)));
                }
            }
        }
    }
}

// ---------------------------------------------------------------------------
// 7) Final head: out[b,t,c] = (y96[b,t,:] . W[c,:]) * std[b,c] + mean[b,c]
//    one wave per (b,t,c)
// ---------------------------------------------------------------------------
__global__ void head_kernel(const float* __restrict__ y96,
                            const float* __restrict__ W,
                            const float* __restrict__ mean,
                            const float* __restrict__ stdv,
                            float* __restrict__ out) {
    int idx = blockIdx.x;                 // 8*96*21
    int c = idx % C_OUT;
    int bt = idx / C_OUT;
    int b = bt / PRED_LEN;
    int lane = threadIdx.x;
    const float* yrow = y96 + (size_t)bt * D_INNER;
    const float* wrow = W + (size_t)c * D_INNER;
    float s = 0.f;
    for (int d = lane; d < D_INNER; d += 64) s += yrow[d] * wrow[d];
    #pragma unroll
    for (int m = 32; m >= 1; m >>= 1) s += __shfl_xor(s, m, 64);
    if (lane == 0)
        out[(size_t)bt * C_OUT + c] = s * stdv[b * C_OUT + c] + mean[b * C_OUT + c];
}

// ---------------------------------------------------------------------------
extern "C" void kernel_launch(void* const* d_in, const int* in_sizes, int n_in,
                              void* d_out, int out_size, void* d_ws, size_t ws_size,
                              hipStream_t stream) {
    const float* x_enc     = (const float*)d_in[0];
    const float* x_mark    = (const float*)d_in[1];
    // d_in[2], d_in[3] (x_dec / x_mark_dec) unused by the forecast path
    const float* conv_w    = (const float*)d_in[4];
    const float* temp_w    = (const float*)d_in[5];
    const float* in_proj_w = (const float*)d_in[6];
    const float* conv1d_w  = (const float*)d_in[7];
    const float* conv1d_b  = (const float*)d_in[8];
    const float* x_proj_w  = (const float*)d_in[9];
    const float* dt_proj_w = (const float*)d_in[10];
    const float* dt_proj_b = (const float*)d_in[11];
    const float* A_log     = (const float*)d_in[12];
    const float* Dp        = (const float*)d_in[13];
    const float* out_proj_w= (const float*)d_in[14];
    const float* head_w    = (const float*)d_in[15];
    float* out = (float*)d_out;
    float* ws = (float*)d_ws;

    // workspace layout (floats)
    size_t off = 0;
    float* mean    = ws + off; off += 256;
    float* stdv    = ws + off; off += 256;
    float* W       = ws + off; off += (size_t)C_OUT * D_INNER;          // 21504
    float* emb     = ws + off; off += (size_t)Bsz * Lseq * D_MODEL;     // 8.4M
    float* xs_raw  = ws + off; off += (size_t)Bsz * Lseq * D_INNER;     // 16.8M
    float* z96     = ws + off; off += (size_t)Bsz * PRED_LEN * D_INNER; // 0.79M
    float* xs_conv = ws + off; off += (size_t)Bsz * Lseq * D_INNER;     // 16.8M
    float* xdbl    = ws + off; off += (size_t)Bsz * Lseq * 64;          // 1.05M
    float* delta   = ws + off; off += (size_t)Bsz * Lseq * D_INNER;     // 16.8M
    float* y96     = ws + off; off += (size_t)Bsz * PRED_LEN * D_INNER; // 0.79M

    const int M = Bsz * Lseq;   // 16384

    // 1) instance-norm stats
    stats_kernel<<<Bsz * ENC_IN, 256, 0, stream>>>(x_enc, mean, stdv);
    // 2) fused output weight
    fuse_w_kernel<<<(C_OUT * D_INNER + 255) / 256, 256, 0, stream>>>(head_w, out_proj_w, W);
    // 3) embedding
    embed_kernel<<<M, 256, 0, stream>>>(x_enc, x_mark, conv_w, temp_w, mean, stdv, emb);
    // 4a) in_proj, xs half only: (16384 x 512) @ (1024 x 512)^T
    gemm_nt<0><<<dim3(D_INNER / 64, M / 64), 256, 0, stream>>>(
        emb, in_proj_w, xs_raw, nullptr, M, D_INNER, D_MODEL, D_MODEL, D_MODEL);
    // 4b) in_proj, z half, last 96 rows per batch only: (768 x 512) @ (1024 x 512)^T
    gemm_nt<3><<<dim3(D_INNER / 64, (Bsz * PRED_LEN) / 64), 256, 0, stream>>>(
        emb, in_proj_w + (size_t)D_INNER * D_MODEL, z96, nullptr,
        Bsz * PRED_LEN, D_INNER, D_MODEL, D_MODEL, D_MODEL);
    // 5) depthwise causal conv + SiLU
    dwconv_kernel<<<(M * D_INNER) / 256, 256, 0, stream>>>(xs_raw, conv1d_w, conv1d_b, xs_conv);
    // 6) x_proj: (16384 x 1024) @ (64 x 1024)^T
    gemm_nt<0><<<dim3(1, M / 64), 256, 0, stream>>>(
        xs_conv, x_proj_w, xdbl, nullptr, M, 64, D_INNER, D_INNER, D_INNER);
    // 7) dt_proj + softplus: (16384 x 32) @ (1024 x 32)^T, A rows from xdbl (ld 64)
    gemm_nt<2><<<dim3(D_INNER / 64, M / 64), 256, 0, stream>>>(
        xdbl, dt_proj_w, delta, dt_proj_b, M, D_INNER, DT_RANK, 64, DT_RANK);
    // 8) selective scan (+ fused gate)
    scan_kernel<<<Bsz * 64, 256, 0, stream>>>(delta, xs_conv, xdbl, A_log, Dp, z96, y96);
    // 9) head + de-normalize
    head_kernel<<<Bsz * PRED_LEN * C_OUT, 64, 0, stream>>>(y96, W, mean, stdv, out);
}